// Round 10
// baseline (244.161 us; speedup 1.0000x reference)
//
#include <hip/hip_runtime.h>
#include <math.h>

// Problem constants (from reference setup_inputs)
constexpr int B = 64;
constexpr int T = 1024;
constexpr int C = 128;
constexpr int L = 256;
constexpr int S = 2 * L + 1;     // 513 extended states
constexpr int TRB = 1024;        // transpose blocks (128 threads each)

template <int N> struct IC { static constexpr int value = N; };

// shfl_up by 1 lane as pure VALU DPP (wave_shr:1), bound_ctrl=1 so lane 0
// reads 0 (the CTC halo boundary).
__device__ __forceinline__ float shr1(float x) {
#if __has_builtin(__builtin_amdgcn_mov_dpp)
    return __int_as_float(__builtin_amdgcn_mov_dpp(
        __float_as_int(x), 0x138 /*WAVE_SHR1*/, 0xf, 0xf, true));
#else
    return __int_as_float(__builtin_amdgcn_update_dpp(
        0, __float_as_int(x), 0x138, 0xf, 0xf, true));
#endif
}

template <int CTRL>
__device__ __forceinline__ float maxdpp(float x) {
#if __has_builtin(__builtin_amdgcn_mov_dpp)
    float t = __int_as_float(__builtin_amdgcn_mov_dpp(
        __float_as_int(x), CTRL, 0xf, 0xf, true));
#else
    float t = __int_as_float(__builtin_amdgcn_update_dpp(
        0, __float_as_int(x), CTRL, 0xf, 0xf, true));
#endif
    return fmaxf(x, t);
}

// Wave64 max-reduce -> wave-uniform value (readlane 63).
__device__ __forceinline__ float wave_max_dpp(float x) {
    x = maxdpp<0x111>(x);   // row_shr:1
    x = maxdpp<0x112>(x);   // row_shr:2
    x = maxdpp<0x114>(x);   // row_shr:4
    x = maxdpp<0x118>(x);   // row_shr:8
    x = maxdpp<0x142>(x);   // row_bcast:15
    x = maxdpp<0x143>(x);   // row_bcast:31
    return __int_as_float(__builtin_amdgcn_readlane(__float_as_int(x), 63));
}

// 4-state CTC step, hand-scheduled (R14's verified asm step, halved).
// hh = alpha[s0-1] supplied by caller. a3's mul placed first among the
// muls so the caller's shr1(a3) DPP is >=4 instrs from the write (the
// hazard recognizer also pads conservatively around inline asm).
__device__ __forceinline__ void core4(float& a0, float& a1, float& a2,
                                      float& a3, float hh, float k0, float k1,
                                      float gb, float g0, float g1) {
    float t0, t1, t2, t3;
    asm volatile(
        "v_add_f32 %[t3], %[a3], %[a2]\n\t"
        "v_add_f32 %[t2], %[a2], %[a1]\n\t"
        "v_add_f32 %[t1], %[a1], %[a0]\n\t"
        "v_add_f32 %[t0], %[a0], %[hh]\n\t"
        "v_fma_f32 %[t3], %[k1], %[a1], %[t3]\n\t"
        "v_fma_f32 %[t1], %[k0], %[hh], %[t1]\n\t"
        "v_mul_f32 %[a3], %[t3], %[g1]\n\t"
        "v_mul_f32 %[a2], %[t2], %[gb]\n\t"
        "v_mul_f32 %[a0], %[t0], %[gb]\n\t"
        "v_mul_f32 %[a1], %[t1], %[g0]"
        : [a0]"+v"(a0), [a1]"+v"(a1), [a2]"+v"(a2), [a3]"+v"(a3),
          [t0]"=&v"(t0), [t1]"=&v"(t1), [t2]"=&v"(t2), [t3]"=&v"(t3)
        : [hh]"v"(hh), [k0]"v"(k0), [k1]"v"(k1),
          [gb]"v"(gb), [g0]"v"(g0), [g1]"v"(g1));
}

// R16: 2-wave state-split CTC, barrier-pipelined.
// Evidence base: cyc/group ~ 5.4 x per-wave source instrs across R6/R10/
// R14; memory restructurings all neutral -> only instrs-per-wave matters.
// Split S=513: w0 = states 0..255, w1 = 256..512 (alpha[255] crosses via
// a 32-slot LDS ring). w0 runs exactly 3 groups ahead (skew % 3 == 0 so
// both waves share the compile-time ring phase); each pipeline slot ends
// in ONE unconditional __syncthreads (no spins -> cannot deadlock; R15's
// spin design is abandoned). Scale domains: both waves fold scale_{G-4}
// into row-0 g's at own group G -> halo slot domains match consumer
// domains EXACTLY (no boundary fix; R15's x-inv fix was a double-scale
// bug). Exponent control: apply-delay 4 is unstable raw (z^4 = z^3 - 1
// has |root|>1); corrected psh' = psh_raw - (p1+p2+p3) gives z^4 = 0
// (deadbeat). lsi tracks applied shifts exactly, so correctness never
// depends on the stability logic.
__global__
__attribute__((amdgpu_waves_per_eu(1, 1)))
__launch_bounds__(128)
void ctc_fused(
    const float* __restrict__ yp,    // [B,T,C] probabilities
    const int*   __restrict__ yt,    // [B,L]
    const int*   __restrict__ il_,   // [B]
    const int*   __restrict__ ll_,   // [B]
    float* __restrict__ out_log,     // [T,B,C]
    float* __restrict__ out_loss)    // scalar, pre-zeroed; atomic mean
{
    const int tid = threadIdx.x;
    if (blockIdx.x >= B) {
        // ---- transpose + log path: one b, 64 consecutive t-rows per block.
        int id = blockIdx.x - B;     // 0..1023
        int bb = id >> 4;            // batch element
        int ck = id & 15;            // which 64-row chunk of T
        const float4* src = (const float4*)yp + ((size_t)bb * T + ck * 64) * 32;
        float4* o4 = (float4*)out_log;
        #pragma unroll
        for (int k = 0; k < 16; ++k) {
            int o = k * 128 + tid;               // 0..2047 (contiguous read)
            float4 v = src[o];
            int tt = ck * 64 + (o >> 5);
            int c4 = o & 31;
            float4 r;
            r.x = __logf(v.x); r.y = __logf(v.y);
            r.z = __logf(v.z); r.w = __logf(v.w);
            o4[((size_t)tt * B + bb) * 32 + c4] = r;
        }
        return;
    }

    // ---- CTC forward path: 2 waves, state-split, skew-3 pipeline ----
    const int lane = tid & 63;
    const int w    = tid >> 6;           // 0: states 0..255, 1: 256..512
    const int b    = blockIdx.x;

    __shared__ float afin[S];                                  // final alphas
    __shared__ __attribute__((aligned(16))) float halo[36];    // 32 ring + dump
    __shared__ float gmx[256][2];        // per-group local maxes (1..255)

    if (tid < 36) halo[tid] = 0.f;       // slot 0 = alpha[255]@row0 = 0
    __syncthreads();

    int il = il_[b]; il = min(max(il, 1), T);
    int ll = ll_[b]; ll = min(max(ll, 1), L);
    const float* yb = yp + (size_t)b * T * C;

    // Lane owns states s0..s0+3, s0 = 256*w + 4*lane; a4 = state 512 on
    // w1 lane63 (junk elsewhere, benign). Odd states s0+1, s0+3 have
    // labels y[li], y[li+1], li = 2*lane + 128*w.
    const int li = 2 * lane + 128 * w;
    int2 y2 = *(const int2*)(yt + b * L + li);           // 8B-aligned
    int yprev = yt[b * L + (li ? li - 1 : 0)];
    float k0 = (li && (y2.x != yprev)) ? 1.f : 0.f;      // skip gate s0+1
    float k1 = (y2.y != y2.x) ? 1.f : 0.f;               // skip gate s0+3
    const int c0 = y2.x, c1 = y2.y;

    // Opaque zero voffset keeps blank loads on the vector memory path.
    int z0; asm volatile("v_mov_b32 %0, 0" : "=v"(z0));

    // Gather ring: 3 buffers, distance-2 prefetch (per wave, own groups).
    float gv[3][4][2], gbv[3][4];
    auto fill = [&](auto Qc, int r0) {
        constexpr int Q = decltype(Qc)::value;
        int r = r0 < T - 4 ? r0 : T - 4;
        const float* rb = yb + (size_t)r * C;
        #pragma unroll
        for (int j = 0; j < 4; ++j) {
            gbv[Q][j]   = rb[j * C + z0];
            gv[Q][j][0] = rb[j * C + c0];
            gv[Q][j][1] = rb[j * C + c1];
        }
    };

    float a0 = 0.f, a1 = 0.f, a2 = 0.f, a3 = 0.f, a4 = 0.f;
    if (tid == 0) { a0 = yb[0]; a1 = yb[c0]; }   // alpha0: states 0,1

    fill(IC<0>{}, 1);                    // group 1 rows (1..4)
    fill(IC<1>{}, 5);                    // group 2 rows (5..8)

    int lsi = 0;                         // accumulated log2 scale (exact)
    int p1 = 0, p2 = 0, p3 = 0;          // last 3 applied shifts (deadbeat)
    const int  Gf  = (il - 1) >> 2;      // full groups
    const int  N   = Gf + 3;             // pipeline slots
    const bool isb = (tid == 64);        // w1 lane 0 (halo consumer)

    // One group of 4 rows for THIS wave (own = wave's group index, phase
    // P = (own-1)%3 compile-time).
    auto gbody = [&](auto Pc, int own) {
        constexpr int P = decltype(Pc)::value;
        constexpr int F = (P + 2) % 3;
        // Fold corrected scale_{own-4} into row-0 g's (exact pow2).
        int qi = own - 4;
        float mm = (qi >= 1) ? fmaxf(gmx[qi][0], gmx[qi][1])
                             : __int_as_float(223 << 23);   // -> ps = 0
        int eb = (__float_as_int(mm) >> 23) & 0xff;
        int pr = 223 - eb;                   // raw shift (350-eb-127)
        int ps = pr - (p1 + p2 + p3);        // deadbeat correction
        ps = ps > 127 ? 127 : (ps < -126 ? -126 : ps);
        float inv = __int_as_float((ps + 127) << 23);
        p3 = p2; p2 = p1; p1 = ps;
        lsi -= ps;
        float fgb = gbv[P][0] * inv, fg0 = gv[P][0][0] * inv,
              fg1 = gv[P][0][1] * inv;
        // w1: halo block = alpha[255] after rows 4*own-4 .. 4*own-1.
        float4 hv = make_float4(0.f, 0.f, 0.f, 0.f);
        if (w == 1) hv = *(const float4*)&halo[(4 * (own - 1)) & 31];
        #pragma unroll
        for (int j = 0; j < 4; ++j) {
            float gbj = (j == 0) ? fgb : gbv[P][j];
            float g0j = (j == 0) ? fg0 : gv[P][j][0];
            float g1j = (j == 0) ? fg1 : gv[P][j][1];
            float hx  = (j == 0) ? hv.x
                                 : (j == 1 ? hv.y : (j == 2 ? hv.z : hv.w));
            float hhv = shr1(a3);
            float hh  = isb ? hx : hhv;
            float t4  = a4 + a3;             // state 512 chain (w1 lane63)
            core4(a0, a1, a2, a3, hh, k0, k1, gbj, g0j, g1j);
            a4 = t4 * gbj;
            if (w == 0)                      // publish alpha[255] per row
                halo[(lane == 63) ? ((4 * own - 3 + j) & 31) : 33] = a3;
        }
        float lm = fmaxf(fmaxf(a0, a1), fmaxf(a2, a3));
        lm = wave_max_dpp(fmaxf(lm, a4));
        if (lane == 0) gmx[own][w] = lm;
        fill(IC<F>{}, 4 * own + 5);          // rows of group own+2
        __builtin_amdgcn_sched_barrier(0x7);
    };

    // One pipeline slot k: w0 does group k (k<=Gf); w1 does group k-3
    // (k>=4). Phases coincide because skew % 3 == 0. Barrier reached by
    // ALL threads unconditionally.
    auto slot = [&](auto Pc, int k) {
        bool act = (w == 0) ? (k <= Gf) : (k >= 4);
        if (act) gbody(Pc, (w == 0) ? k : k - 3);
        __syncthreads();
    };

    int k = 1;
    while (k + 2 <= N) {
        slot(IC<0>{}, k); slot(IC<1>{}, k + 1); slot(IC<2>{}, k + 2);
        k += 3;
    }
    if (k <= N) { slot(IC<0>{}, k); ++k; }
    if (k <= N) { slot(IC<1>{}, k); ++k; }

    // Leftover rows 4Gf+1 .. il-1 (<=3), lockstep, direct loads; both
    // waves in domain <= Gf-4 (consistent with halo slots).
    #pragma unroll
    for (int j = 0; j < 3; ++j) {
        int r = 4 * Gf + 1 + j;
        bool run = (r < il);                 // uniform
        if (run && w == 0) {
            const float* rp = yb + (size_t)r * C;
            float gbj = rp[0], g0j = rp[c0], g1j = rp[c1];
            float hh = shr1(a3);
            core4(a0, a1, a2, a3, hh, k0, k1, gbj, g0j, g1j);
            if (lane == 63) halo[r & 31] = a3;
        }
        __syncthreads();
        if (run && w == 1) {
            const float* rp = yb + (size_t)r * C;
            float gbj = rp[0], g0j = rp[c0], g1j = rp[c1];
            float hvs = halo[(r - 1) & 31];
            float hhv = shr1(a3);
            float hh  = (lane == 0) ? hvs : hhv;
            float t4  = a4 + a3;
            core4(a0, a1, a2, a3, hh, k0, k1, gbj, g0j, g1j);
            a4 = t4 * gbj;
        }
    }
    __syncthreads();

    // Final pending scales q = Gf-3..Gf (same corrected sequence; both
    // waves execute identically -> same domain, same lsi).
    for (int q = Gf - 3; q <= Gf; ++q) {
        if (q >= 1) {
            float mm = fmaxf(gmx[q][0], gmx[q][1]);
            int eb = (__float_as_int(mm) >> 23) & 0xff;
            int pr = 223 - eb;
            int ps = pr - (p1 + p2 + p3);
            ps = ps > 127 ? 127 : (ps < -126 ? -126 : ps);
            float inv = __int_as_float((ps + 127) << 23);
            p3 = p2; p2 = p1; p1 = ps;
            lsi -= ps;
            a0 *= inv; a1 *= inv; a2 *= inv; a3 *= inv; a4 *= inv;
        }
    }

    // Loss: -ln(alpha[2ll-1] + alpha[2ll]) with accumulated scale.
    int s0 = 256 * w + 4 * lane;
    afin[s0 + 0] = a0; afin[s0 + 1] = a1;
    afin[s0 + 2] = a2; afin[s0 + 3] = a3;
    if (w == 1 && lane == 63) afin[512] = a4;
    __syncthreads();
    if (tid == 0) {
        float e1 = afin[2 * ll - 1];
        float e2 = afin[2 * ll];
        float sum = fmaxf(e1 + e2, 1e-37f);
        float loss = -(__log2f(sum) + (float)lsi) * 0.6931471805599453f;  // nats
        atomicAdd(out_loss, loss * (1.0f / (float)B));
    }
}

extern "C" void kernel_launch(void* const* d_in, const int* in_sizes, int n_in,
                              void* d_out, int out_size, void* d_ws, size_t ws_size,
                              hipStream_t stream) {
    const int*   y_true = (const int*)d_in[0];
    const float* y_pred = (const float*)d_in[1];
    const int*   in_len = (const int*)d_in[2];
    const int*   lb_len = (const int*)d_in[3];

    float* out_log  = (float*)d_out;                      // [T,B,C]
    float* out_loss = (float*)d_out + (size_t)T * B * C;  // scalar

    hipMemsetAsync(out_loss, 0, sizeof(float), stream);
    ctc_fused<<<B + TRB, 128, 0, stream>>>(y_pred, y_true, in_len, lb_len,
                                           out_log, out_loss);
}